// Round 9
// baseline (455.813 us; speedup 1.0000x reference)
//
#include <hip/hip_runtime.h>
#include <cstddef>

// Multigrid F-cycle advection, 4096^2 f32, T=4 outer iterations.
// R9: 3 launches/iteration, all full-grid pure-streaming (no LDS barrier
// in fine-grid kernels — R8 post-mortem: staging+barrier serialized the
// memory phases and cost 10 us/iter):
//   1. k_sr_chain : r1 = restrict(smooth(bc(v))) + in-LDS r2,r3,r4,r5
//   2. k_mid      : per-block redundant r5->E6 chain -> local E5/E4/E3 (LDS)
//                   -> writes 64x64 E2 tile.  (E4, E3 never in global)
//   3. k_final    : E1 values computed IN REGISTERS per thread via e1_at
//                   (verbatim R8 staging formula), then
//                   v' = w - smooth(bc(w)), w = v - prolong(E1).
//                   (E1 never in global; no LDS, no barrier)
// All FP op orders identical to R2/R6/R8 (passing, absmax 3.814697e-06).

constexpr float CW = 0.05f;  // CXW == CYW == DT/DX/2

// e_new = (Pc - smooth_zero_pad(P)) + r, reference rounding order.
__device__ __forceinline__ float up_val(float Pc, float Pu, float Pd, float Pl,
                                        float Pr, float rv) {
  float sm = CW * Pu - CW * Pd + CW * Pl + Pc - CW * Pr;
  return (Pc - sm) + rv;
}

// E1[a][b] computed on the fly from E2 + r1 (a,b in [0,2047]).
__device__ __forceinline__ float e1_at(const float* __restrict__ E2,
                                       const float* __restrict__ r1,
                                       int a, int b) {
  const int h = 2048, s2 = 1024;
  float Pc = E2[(size_t)(a >> 1) * s2 + (b >> 1)];
  float Pu = (a > 0)     ? E2[(size_t)((a - 1) >> 1) * s2 + (b >> 1)] : 0.0f;
  float Pd = (a < h - 1) ? E2[(size_t)((a + 1) >> 1) * s2 + (b >> 1)] : 0.0f;
  float Pl = (b > 0)     ? E2[(size_t)(a >> 1) * s2 + ((b - 1) >> 1)] : 0.0f;
  float Pr = (b < h - 1) ? E2[(size_t)(a >> 1) * s2 + ((b + 1) >> 1)] : 0.0f;
  return up_val(Pc, Pu, Pd, Pl, Pr, r1[(size_t)a * h + b]);
}

// ---------------------------------------------------------------------------
// k_sr_chain: block computes 64x64 r1 tile (R2 SR per-unit code), then
// in-LDS restricts to r2 (32x32), r3 (16x16), r4 (8x8), r5 (4x4). (verbatim R6)
__global__ __launch_bounds__(256) void k_sr_chain(
    const float* __restrict__ v, float* __restrict__ r1,
    float* __restrict__ r2, float* __restrict__ r3,
    float* __restrict__ r4, float* __restrict__ r5) {
  const int n = 4096, h = 2048;
  __shared__ float r1s[64][65];
  __shared__ float r2s[32][33];
  __shared__ float r3s[16][17];
  __shared__ float r4s[8][9];
  int tid = threadIdx.x;
  int bx = blockIdx.x, by = blockIdx.y;
  int ty0 = by * 64, tx0 = bx * 64;

#pragma unroll
  for (int k = 0; k < 4; ++k) {
    int u = tid + 256 * k;
    int uy = u >> 5, ux = u & 31;
    int bi = (ty0 >> 1) + uy;
    int bj = (tx0 >> 1) + ux;
    int c0 = 4 * bj;
    int cl = max(c0 - 1, 0), cr = min(c0 + 4, n - 1);
    float a[6][6];
#pragma unroll
    for (int rr = 0; rr < 6; ++rr) {
      int R = min(max(4 * bi - 1 + rr, 0), n - 1);
      const float* row = v + (size_t)R * n;
      float4 m = *reinterpret_cast<const float4*>(row + c0);
      a[rr][0] = row[cl];
      a[rr][1] = m.x; a[rr][2] = m.y; a[rr][3] = m.z; a[rr][4] = m.w;
      a[rr][5] = row[cr];
    }
#pragma unroll
    for (int oi = 0; oi < 2; ++oi) {
      float2 o;
#pragma unroll
      for (int oj = 0; oj < 2; ++oj) {
        float s[2][2];
#pragma unroll
        for (int p = 0; p < 2; ++p)
#pragma unroll
          for (int q = 0; q < 2; ++q) {
            int P = 2 * oi + p, Q = 2 * oj + q;
            s[p][q] = CW * a[P][Q + 1] - CW * a[P + 2][Q + 1]
                    + CW * a[P + 1][Q] + a[P + 1][Q + 1] - CW * a[P + 1][Q + 2];
          }
        float val = 0.25f * (((s[0][0] + s[1][0]) + s[0][1]) + s[1][1]);
        (oj ? o.y : o.x) = val;
        r1s[2 * uy + oi][2 * ux + oj] = val;
      }
      *reinterpret_cast<float2*>(r1 + (size_t)(2 * bi + oi) * h + 2 * bj) = o;
    }
  }
  __syncthreads();

#pragma unroll
  for (int k = 0; k < 4; ++k) {
    int idx = tid + 256 * k;
    int I = idx >> 5, J = idx & 31;
    float val = 0.25f * (((r1s[2 * I][2 * J] + r1s[2 * I + 1][2 * J])
                          + r1s[2 * I][2 * J + 1]) + r1s[2 * I + 1][2 * J + 1]);
    r2s[I][J] = val;
    r2[(size_t)(32 * by + I) * 1024 + 32 * bx + J] = val;
  }
  __syncthreads();

  {
    int I = tid >> 4, J = tid & 15;
    float val = 0.25f * (((r2s[2 * I][2 * J] + r2s[2 * I + 1][2 * J])
                          + r2s[2 * I][2 * J + 1]) + r2s[2 * I + 1][2 * J + 1]);
    r3s[I][J] = val;
    r3[(size_t)(16 * by + I) * 512 + 16 * bx + J] = val;
  }
  __syncthreads();

  if (tid < 64) {
    int I = tid >> 3, J = tid & 7;
    float val = 0.25f * (((r3s[2 * I][2 * J] + r3s[2 * I + 1][2 * J])
                          + r3s[2 * I][2 * J + 1]) + r3s[2 * I + 1][2 * J + 1]);
    r4s[I][J] = val;
    r4[(size_t)(8 * by + I) * 256 + 8 * bx + J] = val;
  }
  __syncthreads();

  if (tid < 16) {
    int I = tid >> 2, J = tid & 3;
    float val = 0.25f * (((r4s[2 * I][2 * J] + r4s[2 * I + 1][2 * J])
                          + r4s[2 * I][2 * J + 1]) + r4s[2 * I + 1][2 * J + 1]);
    r5[(size_t)(4 * by + I) * 128 + 4 * bx + J] = val;
  }
}

// ---------------------------------------------------------------------------
// k_mid: 16x16 blocks x 256 thr. Each block redundantly computes the
// r5->r9 -> E9..E6 chain in LDS; then local E5 rows (10), local E4 (18x18),
// local E3 (34x34), and writes its 64x64 E2 tile = up(E3, r2). (verbatim R8)
__global__ __launch_bounds__(256, 1) void k_mid(
    const float* __restrict__ r5, const float* __restrict__ r4,
    const float* __restrict__ r3, const float* __restrict__ r2,
    float* __restrict__ E2) {
  __shared__ float r5s[128 * 128];
  __shared__ float r6s[64 * 64];
  __shared__ float r7s[32 * 32];
  __shared__ float r8s[16 * 16];
  __shared__ float r9s[8 * 8];
  __shared__ float E8s[16 * 16];
  __shared__ float E7s[32 * 32];
  __shared__ float E6s[64 * 64];
  __shared__ float e5r[10][128];
  __shared__ float e4s[18][20];
  __shared__ float e3s[34][35];
  int tid = threadIdx.x;
  int bx = blockIdx.x, by = blockIdx.y;

  auto up_lds = [&](const float* Ep, const float* rr, int i, int c, int nn) {
    int ss = nn >> 1;
    float Pc = Ep[(i >> 1) * ss + (c >> 1)];
    float Pu = (i > 0)      ? Ep[((i - 1) >> 1) * ss + (c >> 1)] : 0.0f;
    float Pd = (i < nn - 1) ? Ep[((i + 1) >> 1) * ss + (c >> 1)] : 0.0f;
    float Pl = (c > 0)      ? Ep[(i >> 1) * ss + ((c - 1) >> 1)] : 0.0f;
    float Pr = (c < nn - 1) ? Ep[(i >> 1) * ss + ((c + 1) >> 1)] : 0.0f;
    return up_val(Pc, Pu, Pd, Pl, Pr, rr[i * nn + c]);
  };

  for (int idx = tid; idx < 4096; idx += 256)
    reinterpret_cast<float4*>(r5s)[idx] = reinterpret_cast<const float4*>(r5)[idx];
  __syncthreads();
  for (int idx = tid; idx < 64 * 64; idx += 256) {
    int I = idx >> 6, J = idx & 63;
    float a = r5s[(2 * I) * 128 + 2 * J],     b = r5s[(2 * I + 1) * 128 + 2 * J];
    float c = r5s[(2 * I) * 128 + 2 * J + 1], d = r5s[(2 * I + 1) * 128 + 2 * J + 1];
    r6s[idx] = 0.25f * (((a + b) + c) + d);
  }
  __syncthreads();
  for (int idx = tid; idx < 32 * 32; idx += 256) {
    int I = idx >> 5, J = idx & 31;
    float a = r6s[(2 * I) * 64 + 2 * J],     b = r6s[(2 * I + 1) * 64 + 2 * J];
    float c = r6s[(2 * I) * 64 + 2 * J + 1], d = r6s[(2 * I + 1) * 64 + 2 * J + 1];
    r7s[idx] = 0.25f * (((a + b) + c) + d);
  }
  __syncthreads();
  if (tid < 16 * 16) {
    int I = tid >> 4, J = tid & 15;
    float a = r7s[(2 * I) * 32 + 2 * J],     b = r7s[(2 * I + 1) * 32 + 2 * J];
    float c = r7s[(2 * I) * 32 + 2 * J + 1], d = r7s[(2 * I + 1) * 32 + 2 * J + 1];
    r8s[tid] = 0.25f * (((a + b) + c) + d);
  }
  __syncthreads();
  if (tid < 8 * 8) {
    int I = tid >> 3, J = tid & 7;
    float a = r8s[(2 * I) * 16 + 2 * J],     b = r8s[(2 * I + 1) * 16 + 2 * J];
    float c = r8s[(2 * I) * 16 + 2 * J + 1], d = r8s[(2 * I + 1) * 16 + 2 * J + 1];
    r9s[tid] = 0.25f * (((a + b) + c) + d);
  }
  __syncthreads();
  if (tid < 16 * 16)
    E8s[tid] = up_lds(r9s, r8s, tid >> 4, tid & 15, 16);
  __syncthreads();
  if (tid < 32 * 32)
    E7s[tid] = up_lds(E8s, r7s, tid >> 5, tid & 31, 32);
  __syncthreads();
  for (int idx = tid; idx < 64 * 64; idx += 256)
    E6s[idx] = up_lds(E7s, r6s, idx >> 6, idx & 63, 64);
  __syncthreads();
  for (int idx = tid; idx < 10 * 128; idx += 256) {
    int t = idx >> 7, c = idx & 127;
    int i = min(max(8 * by - 1 + t, 0), 127);
    e5r[t][c] = up_lds(E6s, r5s, i, c, 128);
  }
  __syncthreads();
  for (int idx = tid; idx < 18 * 18; idx += 256) {
    int er = idx / 18, ec = idx % 18;
    int ga = 16 * by - 1 + er, gb = 16 * bx - 1 + ec;
    if (ga >= 0 && ga < 256 && gb >= 0 && gb < 256) {
      float Pc = e5r[(ga >> 1) - (8 * by - 1)][gb >> 1];
      float Pu = (ga > 0)   ? e5r[((ga - 1) >> 1) - (8 * by - 1)][gb >> 1] : 0.0f;
      float Pd = (ga < 255) ? e5r[((ga + 1) >> 1) - (8 * by - 1)][gb >> 1] : 0.0f;
      float Pl = (gb > 0)   ? e5r[(ga >> 1) - (8 * by - 1)][(gb - 1) >> 1] : 0.0f;
      float Pr = (gb < 255) ? e5r[(ga >> 1) - (8 * by - 1)][(gb + 1) >> 1] : 0.0f;
      e4s[er][ec] = up_val(Pc, Pu, Pd, Pl, Pr, r4[(size_t)ga * 256 + gb]);
    }
  }
  __syncthreads();
  for (int idx = tid; idx < 34 * 34; idx += 256) {
    int er = idx / 34, ec = idx % 34;
    int gr = 32 * by - 1 + er, gc = 32 * bx - 1 + ec;
    float val = 0.0f;
    if (gr >= 0 && gr < 512 && gc >= 0 && gc < 512) {
      int e4r0 = 16 * by - 1, e4c0 = 16 * bx - 1;
      float Pc = e4s[(gr >> 1) - e4r0][(gc >> 1) - e4c0];
      float Pu = (gr > 0)   ? e4s[((gr - 1) >> 1) - e4r0][(gc >> 1) - e4c0] : 0.0f;
      float Pd = (gr < 511) ? e4s[((gr + 1) >> 1) - e4r0][(gc >> 1) - e4c0] : 0.0f;
      float Pl = (gc > 0)   ? e4s[(gr >> 1) - e4r0][((gc - 1) >> 1) - e4c0] : 0.0f;
      float Pr = (gc < 511) ? e4s[(gr >> 1) - e4r0][((gc + 1) >> 1) - e4c0] : 0.0f;
      val = up_val(Pc, Pu, Pd, Pl, Pr, r3[(size_t)gr * 512 + gc]);
    }
    e3s[er][ec] = val;
  }
  __syncthreads();
  int br0 = 32 * by - 1, bc0 = 32 * bx - 1;
#pragma unroll
  for (int k = 0; k < 4; ++k) {
    int u = tid + 256 * k;
    int rr = u >> 4, f = u & 15;
    int gR = 64 * by + rr;
    int gC = 64 * bx + 4 * f;
    int rc = (gR >> 1) - br0;
    int ru = ((gR - 1) >> 1) - br0;
    int rd = ((gR + 1) >> 1) - br0;
    float4 rv = *reinterpret_cast<const float4*>(r2 + (size_t)gR * 1024 + gC);
    float4 o;
#pragma unroll
    for (int q = 0; q < 4; ++q) {
      int c = gC + q;
      int lc = (c >> 1) - bc0;
      float Pc = e3s[rc][lc];
      float Pu = (gR > 0)    ? e3s[ru][lc] : 0.0f;
      float Pd = (gR < 1023) ? e3s[rd][lc] : 0.0f;
      float Pl = (c > 0)     ? e3s[rc][((c - 1) >> 1) - bc0] : 0.0f;
      float Pr = (c < 1023)  ? e3s[rc][((c + 1) >> 1) - bc0] : 0.0f;
      (&o.x)[q] = up_val(Pc, Pu, Pd, Pl, Pr, (&rv.x)[q]);
    }
    *reinterpret_cast<float4*>(E2 + (size_t)gR * 1024 + gC) = o;
  }
}

// ---------------------------------------------------------------------------
// k_final: e[t][c] = E1 values computed in registers (e1_at); then
// out = w - smooth(bc(w)), w = v - prolong(E1). Body verbatim R2.
__global__ __launch_bounds__(256) void k_final(
    const float* __restrict__ v, const float* __restrict__ E2,
    const float* __restrict__ r1, float* __restrict__ out) {
  const int n = 4096;
  int J = blockIdx.x * blockDim.x + threadIdx.x;
  int i = blockIdx.y * blockDim.y + threadIdx.y;
  int c0 = 4 * J;
  int cl = max(c0 - 1, 0), cr = min(c0 + 4, n - 1);
  int ecl = cl >> 1, ecr = cr >> 1;

  float e[3][4];
  int ers0 = max(2 * i - 1, 0) >> 1;
  int ers2 = min(2 * i + 2, n - 1) >> 1;
  const int ers[3] = {ers0, i, ers2};
#pragma unroll
  for (int t = 0; t < 3; ++t) {
    int a = ers[t];
    e[t][0] = e1_at(E2, r1, a, ecl);
    e[t][1] = e1_at(E2, r1, a, 2 * J);
    e[t][2] = e1_at(E2, r1, a, 2 * J + 1);
    e[t][3] = e1_at(E2, r1, a, ecr);
  }

  float w[4][6];
  const int tmap[4] = {0, 1, 1, 2};
#pragma unroll
  for (int rr = 0; rr < 4; ++rr) {
    int R = min(max(2 * i - 1 + rr, 0), n - 1);
    int t = tmap[rr];
    const float* vrow = v + (size_t)R * n;
    float4 m = *reinterpret_cast<const float4*>(vrow + c0);
    w[rr][0] = vrow[cl] - e[t][0];
    w[rr][1] = m.x - e[t][1];
    w[rr][2] = m.y - e[t][1];
    w[rr][3] = m.z - e[t][2];
    w[rr][4] = m.w - e[t][2];
    w[rr][5] = vrow[cr] - e[t][3];
  }
#pragma unroll
  for (int a = 0; a < 2; ++a) {
    float4 o;
#pragma unroll
    for (int qq = 0; qq < 4; ++qq) {
      float ce = w[a + 1][qq + 1];
      float sm = CW * w[a][qq + 1] - CW * w[a + 2][qq + 1]
               + CW * w[a + 1][qq] + ce - CW * w[a + 1][qq + 2];
      (&o.x)[qq] = ce - sm;
    }
    *reinterpret_cast<float4*>(out + (size_t)(2 * i + a) * n + c0) = o;
  }
}

// ---------------------------------------------------------------------------
extern "C" void kernel_launch(void* const* d_in, const int* in_sizes, int n_in,
                              void* d_out, int out_size, void* d_ws, size_t ws_size,
                              hipStream_t stream) {
  (void)in_sizes; (void)n_in; (void)out_size;
  float* u = (float*)d_in[0];
  float* out = (float*)d_out;
  char* ws = (char*)d_ws;

  size_t off = 0;
  auto alloc = [&](size_t elems) {
    float* p = (float*)(ws + off);
    off += (elems * sizeof(float) + 255) & ~(size_t)255;
    return p;
  };
  float* r1 = alloc(2048 * 2048);
  float* r2 = alloc(1024 * 1024);
  float* r3 = alloc(512 * 512);
  float* r4 = alloc(256 * 256);
  float* r5 = alloc(128 * 128);
  float* E2 = alloc(1024 * 1024);
  size_t pool = off;
  const size_t VB = (size_t)4096 * 4096 * sizeof(float);
  bool big = ws_size >= pool + VB;
  float* vws = (float*)(ws + pool);

  auto iterate = [&](const float* vin, float* vout) {
    k_sr_chain<<<dim3(32, 32), 256, 0, stream>>>(vin, r1, r2, r3, r4, r5);
    k_mid<<<dim3(16, 16), 256, 0, stream>>>(r5, r4, r3, r2, E2);
    k_final<<<dim3(16, 512), dim3(64, 4), 0, stream>>>(vin, E2, r1, vout);
  };

  if (big) {
    iterate(u, vws);
    iterate(vws, out);
    iterate(out, vws);
    iterate(vws, out);
  } else {
    iterate(u, out);
    iterate(out, u);
    iterate(u, out);
    iterate(out, u);
    hipMemcpyAsync(out, u, VB, hipMemcpyDeviceToDevice, stream);
  }
}

// Round 10
// 397.928 us; speedup vs baseline: 1.1455x; 1.1455x over previous
//
#include <hip/hip_runtime.h>
#include <cstddef>

// Multigrid F-cycle advection, 4096^2 f32, T=4 outer iterations.
// R10: best-known split structure (R6) + k_mid consolidation + sliding-window
// sr_chain. 4 launches/iteration:
//   1. k_sr_chain : r1 = restrict(smooth(bc(v))) via 4x4-outputs/thread
//                   sliding window (40 load-instr/16 outputs, was 72/16),
//                   + in-LDS restrict chain r2,r3,r4,r5
//   2. k_mid      : per-block redundant r5->E6 chain -> local E5/E4/E3 (LDS)
//                   -> writes 64x64 E2 tile (verbatim R8/R9, proven)
//   3. k_up(2048) : E1 = up(E2, r1)  (streaming; E1 round-trip is CHEAPER
//                   than fusing it into k_final — R8/R9 post-mortems)
//   4. k_final    : v' = w - smooth(bc(w)), w = v - prolong(E1) (verbatim R2)
// All FP op orders identical to R2/R6 (passing, absmax 3.814697e-06).

constexpr float CW = 0.05f;  // CXW == CYW == DT/DX/2

// e_new = (Pc - smooth_zero_pad(P)) + r, reference rounding order.
__device__ __forceinline__ float up_val(float Pc, float Pu, float Pd, float Pl,
                                        float Pr, float rv) {
  float sm = CW * Pu - CW * Pd + CW * Pl + Pc - CW * Pr;
  return (Pc - sm) + rv;
}

// ---------------------------------------------------------------------------
// k_sr_chain: 16x16 threads; each thread computes a 4x4 r1 tile by sliding a
// 4-row x 10-col v register window (rows shift by 2 per output row). Then the
// block's 64x64 r1 tile chains to r2,r3,r4,r5 in LDS (verbatim R6 phases).
__global__ __launch_bounds__(256) void k_sr_chain(
    const float* __restrict__ v, float* __restrict__ r1,
    float* __restrict__ r2, float* __restrict__ r3,
    float* __restrict__ r4, float* __restrict__ r5) {
  const int n = 4096, h = 2048;
  __shared__ float r1s[64][65];
  __shared__ float r2s[32][33];
  __shared__ float r3s[16][17];
  __shared__ float r4s[8][9];
  int tid = threadIdx.x;
  int tx = tid & 15, ty = tid >> 4;
  int bx = blockIdx.x, by = blockIdx.y;
  int g0 = 64 * by + 4 * ty;   // first r1 row of this thread
  int h0 = 64 * bx + 4 * tx;   // first r1 col
  int C0 = 2 * h0;             // v col of first float4 (16B aligned)
  int cl = max(C0 - 1, 0), cr = min(C0 + 8, n - 1);

  float va[4][10];
  auto loadrow = [&](int R, float* dst) {
    R = min(max(R, 0), n - 1);
    const float* row = v + (size_t)R * n;
    float4 m0 = *reinterpret_cast<const float4*>(row + C0);
    float4 m1 = *reinterpret_cast<const float4*>(row + C0 + 4);
    dst[0] = row[cl];
    dst[1] = m0.x; dst[2] = m0.y; dst[3] = m0.z; dst[4] = m0.w;
    dst[5] = m1.x; dst[6] = m1.y; dst[7] = m1.z; dst[8] = m1.w;
    dst[9] = row[cr];
  };
  // initial window: v rows 2g0-1 .. 2g0+2
#pragma unroll
  for (int r = 0; r < 4; ++r) loadrow(2 * g0 - 1 + r, va[r]);

#pragma unroll
  for (int rr = 0; rr < 4; ++rr) {
    int g = g0 + rr;
    float4 o;
#pragma unroll
    for (int cc = 0; cc < 4; ++cc) {
      float s[2][2];
#pragma unroll
      for (int p = 0; p < 2; ++p)
#pragma unroll
        for (int q = 0; q < 2; ++q) {
          // smooth at v row 2g+p, col C0-1 + (2cc+1+q)
          s[p][q] = CW * va[p][2 * cc + 1 + q] - CW * va[p + 2][2 * cc + 1 + q]
                  + CW * va[p + 1][2 * cc + q] + va[p + 1][2 * cc + 1 + q]
                  - CW * va[p + 1][2 * cc + 2 + q];
        }
      float val = 0.25f * (((s[0][0] + s[1][0]) + s[0][1]) + s[1][1]);
      (&o.x)[cc] = val;
      r1s[4 * ty + rr][4 * tx + cc] = val;
    }
    *reinterpret_cast<float4*>(r1 + (size_t)g * h + h0) = o;
    if (rr < 3) {
      // slide window down by 2 v rows (register moves, FP-transparent)
#pragma unroll
      for (int c = 0; c < 10; ++c) { va[0][c] = va[2][c]; va[1][c] = va[3][c]; }
      loadrow(2 * g + 3, va[2]);
      loadrow(2 * g + 4, va[3]);
    }
  }
  __syncthreads();

  // chain phases (verbatim R6)
#pragma unroll
  for (int k = 0; k < 4; ++k) {
    int idx = tid + 256 * k;
    int I = idx >> 5, J = idx & 31;
    float val = 0.25f * (((r1s[2 * I][2 * J] + r1s[2 * I + 1][2 * J])
                          + r1s[2 * I][2 * J + 1]) + r1s[2 * I + 1][2 * J + 1]);
    r2s[I][J] = val;
    r2[(size_t)(32 * by + I) * 1024 + 32 * bx + J] = val;
  }
  __syncthreads();
  {
    int I = tid >> 4, J = tid & 15;
    float val = 0.25f * (((r2s[2 * I][2 * J] + r2s[2 * I + 1][2 * J])
                          + r2s[2 * I][2 * J + 1]) + r2s[2 * I + 1][2 * J + 1]);
    r3s[I][J] = val;
    r3[(size_t)(16 * by + I) * 512 + 16 * bx + J] = val;
  }
  __syncthreads();
  if (tid < 64) {
    int I = tid >> 3, J = tid & 7;
    float val = 0.25f * (((r3s[2 * I][2 * J] + r3s[2 * I + 1][2 * J])
                          + r3s[2 * I][2 * J + 1]) + r3s[2 * I + 1][2 * J + 1]);
    r4s[I][J] = val;
    r4[(size_t)(8 * by + I) * 256 + 8 * bx + J] = val;
  }
  __syncthreads();
  if (tid < 16) {
    int I = tid >> 2, J = tid & 3;
    float val = 0.25f * (((r4s[2 * I][2 * J] + r4s[2 * I + 1][2 * J])
                          + r4s[2 * I][2 * J + 1]) + r4s[2 * I + 1][2 * J + 1]);
    r5[(size_t)(4 * by + I) * 128 + 4 * bx + J] = val;
  }
}

// ---------------------------------------------------------------------------
// k_mid: verbatim R8/R9 (proven bit-exact). Per-block redundant coarse chain
// in LDS -> local E5/E4/E3 -> writes 64x64 E2 tile.
__global__ __launch_bounds__(256, 1) void k_mid(
    const float* __restrict__ r5, const float* __restrict__ r4,
    const float* __restrict__ r3, const float* __restrict__ r2,
    float* __restrict__ E2) {
  __shared__ float r5s[128 * 128];
  __shared__ float r6s[64 * 64];
  __shared__ float r7s[32 * 32];
  __shared__ float r8s[16 * 16];
  __shared__ float r9s[8 * 8];
  __shared__ float E8s[16 * 16];
  __shared__ float E7s[32 * 32];
  __shared__ float E6s[64 * 64];
  __shared__ float e5r[10][128];
  __shared__ float e4s[18][20];
  __shared__ float e3s[34][35];
  int tid = threadIdx.x;
  int bx = blockIdx.x, by = blockIdx.y;

  auto up_lds = [&](const float* Ep, const float* rr, int i, int c, int nn) {
    int ss = nn >> 1;
    float Pc = Ep[(i >> 1) * ss + (c >> 1)];
    float Pu = (i > 0)      ? Ep[((i - 1) >> 1) * ss + (c >> 1)] : 0.0f;
    float Pd = (i < nn - 1) ? Ep[((i + 1) >> 1) * ss + (c >> 1)] : 0.0f;
    float Pl = (c > 0)      ? Ep[(i >> 1) * ss + ((c - 1) >> 1)] : 0.0f;
    float Pr = (c < nn - 1) ? Ep[(i >> 1) * ss + ((c + 1) >> 1)] : 0.0f;
    return up_val(Pc, Pu, Pd, Pl, Pr, rr[i * nn + c]);
  };

  for (int idx = tid; idx < 4096; idx += 256)
    reinterpret_cast<float4*>(r5s)[idx] = reinterpret_cast<const float4*>(r5)[idx];
  __syncthreads();
  for (int idx = tid; idx < 64 * 64; idx += 256) {
    int I = idx >> 6, J = idx & 63;
    float a = r5s[(2 * I) * 128 + 2 * J],     b = r5s[(2 * I + 1) * 128 + 2 * J];
    float c = r5s[(2 * I) * 128 + 2 * J + 1], d = r5s[(2 * I + 1) * 128 + 2 * J + 1];
    r6s[idx] = 0.25f * (((a + b) + c) + d);
  }
  __syncthreads();
  for (int idx = tid; idx < 32 * 32; idx += 256) {
    int I = idx >> 5, J = idx & 31;
    float a = r6s[(2 * I) * 64 + 2 * J],     b = r6s[(2 * I + 1) * 64 + 2 * J];
    float c = r6s[(2 * I) * 64 + 2 * J + 1], d = r6s[(2 * I + 1) * 64 + 2 * J + 1];
    r7s[idx] = 0.25f * (((a + b) + c) + d);
  }
  __syncthreads();
  if (tid < 16 * 16) {
    int I = tid >> 4, J = tid & 15;
    float a = r7s[(2 * I) * 32 + 2 * J],     b = r7s[(2 * I + 1) * 32 + 2 * J];
    float c = r7s[(2 * I) * 32 + 2 * J + 1], d = r7s[(2 * I + 1) * 32 + 2 * J + 1];
    r8s[tid] = 0.25f * (((a + b) + c) + d);
  }
  __syncthreads();
  if (tid < 8 * 8) {
    int I = tid >> 3, J = tid & 7;
    float a = r8s[(2 * I) * 16 + 2 * J],     b = r8s[(2 * I + 1) * 16 + 2 * J];
    float c = r8s[(2 * I) * 16 + 2 * J + 1], d = r8s[(2 * I + 1) * 16 + 2 * J + 1];
    r9s[tid] = 0.25f * (((a + b) + c) + d);
  }
  __syncthreads();
  if (tid < 16 * 16)
    E8s[tid] = up_lds(r9s, r8s, tid >> 4, tid & 15, 16);
  __syncthreads();
  if (tid < 32 * 32)
    E7s[tid] = up_lds(E8s, r7s, tid >> 5, tid & 31, 32);
  __syncthreads();
  for (int idx = tid; idx < 64 * 64; idx += 256)
    E6s[idx] = up_lds(E7s, r6s, idx >> 6, idx & 63, 64);
  __syncthreads();
  for (int idx = tid; idx < 10 * 128; idx += 256) {
    int t = idx >> 7, c = idx & 127;
    int i = min(max(8 * by - 1 + t, 0), 127);
    e5r[t][c] = up_lds(E6s, r5s, i, c, 128);
  }
  __syncthreads();
  for (int idx = tid; idx < 18 * 18; idx += 256) {
    int er = idx / 18, ec = idx % 18;
    int ga = 16 * by - 1 + er, gb = 16 * bx - 1 + ec;
    if (ga >= 0 && ga < 256 && gb >= 0 && gb < 256) {
      float Pc = e5r[(ga >> 1) - (8 * by - 1)][gb >> 1];
      float Pu = (ga > 0)   ? e5r[((ga - 1) >> 1) - (8 * by - 1)][gb >> 1] : 0.0f;
      float Pd = (ga < 255) ? e5r[((ga + 1) >> 1) - (8 * by - 1)][gb >> 1] : 0.0f;
      float Pl = (gb > 0)   ? e5r[(ga >> 1) - (8 * by - 1)][(gb - 1) >> 1] : 0.0f;
      float Pr = (gb < 255) ? e5r[(ga >> 1) - (8 * by - 1)][(gb + 1) >> 1] : 0.0f;
      e4s[er][ec] = up_val(Pc, Pu, Pd, Pl, Pr, r4[(size_t)ga * 256 + gb]);
    }
  }
  __syncthreads();
  for (int idx = tid; idx < 34 * 34; idx += 256) {
    int er = idx / 34, ec = idx % 34;
    int gr = 32 * by - 1 + er, gc = 32 * bx - 1 + ec;
    float val = 0.0f;
    if (gr >= 0 && gr < 512 && gc >= 0 && gc < 512) {
      int e4r0 = 16 * by - 1, e4c0 = 16 * bx - 1;
      float Pc = e4s[(gr >> 1) - e4r0][(gc >> 1) - e4c0];
      float Pu = (gr > 0)   ? e4s[((gr - 1) >> 1) - e4r0][(gc >> 1) - e4c0] : 0.0f;
      float Pd = (gr < 511) ? e4s[((gr + 1) >> 1) - e4r0][(gc >> 1) - e4c0] : 0.0f;
      float Pl = (gc > 0)   ? e4s[(gr >> 1) - e4r0][((gc - 1) >> 1) - e4c0] : 0.0f;
      float Pr = (gc < 511) ? e4s[(gr >> 1) - e4r0][((gc + 1) >> 1) - e4c0] : 0.0f;
      val = up_val(Pc, Pu, Pd, Pl, Pr, r3[(size_t)gr * 512 + gc]);
    }
    e3s[er][ec] = val;
  }
  __syncthreads();
  int br0 = 32 * by - 1, bc0 = 32 * bx - 1;
#pragma unroll
  for (int k = 0; k < 4; ++k) {
    int u = tid + 256 * k;
    int rr = u >> 4, f = u & 15;
    int gR = 64 * by + rr;
    int gC = 64 * bx + 4 * f;
    int rc = (gR >> 1) - br0;
    int ru = ((gR - 1) >> 1) - br0;
    int rd = ((gR + 1) >> 1) - br0;
    float4 rv = *reinterpret_cast<const float4*>(r2 + (size_t)gR * 1024 + gC);
    float4 o;
#pragma unroll
    for (int q = 0; q < 4; ++q) {
      int c = gC + q;
      int lc = (c >> 1) - bc0;
      float Pc = e3s[rc][lc];
      float Pu = (gR > 0)    ? e3s[ru][lc] : 0.0f;
      float Pd = (gR < 1023) ? e3s[rd][lc] : 0.0f;
      float Pl = (c > 0)     ? e3s[rc][((c - 1) >> 1) - bc0] : 0.0f;
      float Pr = (c < 1023)  ? e3s[rc][((c + 1) >> 1) - bc0] : 0.0f;
      (&o.x)[q] = up_val(Pc, Pu, Pd, Pl, Pr, (&rv.x)[q]);
    }
    *reinterpret_cast<float4*>(E2 + (size_t)gR * 1024 + gC) = o;
  }
}

// ---------------------------------------------------------------------------
// k_up (n=2048): E1 = up(E2, r1). Verbatim R2/R6.
__global__ __launch_bounds__(256) void k_up(
    const float* __restrict__ Ep, const float* __restrict__ r,
    float* __restrict__ Eo, int n) {
  int s = n >> 1;
  int j = blockIdx.x * blockDim.x + threadIdx.x;
  int i = blockIdx.y * blockDim.y + threadIdx.y;
  if (i >= s || j >= (n >> 2)) return;
  const float* ec = Ep + (size_t)i * s + 2 * j;
  float epc0 = ec[0], epc1 = ec[1];
  float epl = (j > 0) ? ec[-1] : 0.0f;
  float epr = (2 * j + 2 < s) ? ec[2] : 0.0f;
  float epu0 = 0.0f, epu1 = 0.0f, epd0 = 0.0f, epd1 = 0.0f;
  if (i > 0)     { epu0 = ec[-s]; epu1 = ec[-s + 1]; }
  if (i < s - 1) { epd0 = ec[s];  epd1 = ec[s + 1]; }
  {
    float4 rv = *reinterpret_cast<const float4*>(r + (size_t)(2 * i) * n + 4 * j);
    float4 o;
    o.x = up_val(epc0, epu0, epc0, epl,  epc0, rv.x);
    o.y = up_val(epc0, epu0, epc0, epc0, epc1, rv.y);
    o.z = up_val(epc1, epu1, epc1, epc0, epc1, rv.z);
    o.w = up_val(epc1, epu1, epc1, epc1, epr,  rv.w);
    *reinterpret_cast<float4*>(Eo + (size_t)(2 * i) * n + 4 * j) = o;
  }
  {
    float4 rv = *reinterpret_cast<const float4*>(r + (size_t)(2 * i + 1) * n + 4 * j);
    float4 o;
    o.x = up_val(epc0, epc0, epd0, epl,  epc0, rv.x);
    o.y = up_val(epc0, epc0, epd0, epc0, epc1, rv.y);
    o.z = up_val(epc1, epc1, epd1, epc0, epc1, rv.z);
    o.w = up_val(epc1, epc1, epd1, epc1, epr,  rv.w);
    *reinterpret_cast<float4*>(Eo + (size_t)(2 * i + 1) * n + 4 * j) = o;
  }
}

// ---------------------------------------------------------------------------
// out = w - smooth(bc(w)), w = v - prolong(E1).  (verbatim R2/R6)
__global__ __launch_bounds__(256) void k_final(
    const float* __restrict__ v, const float* __restrict__ E1,
    float* __restrict__ out) {
  const int n = 4096, h = 2048;
  int J = blockIdx.x * blockDim.x + threadIdx.x;
  int i = blockIdx.y * blockDim.y + threadIdx.y;
  int c0 = 4 * J;
  int cl = max(c0 - 1, 0), cr = min(c0 + 4, n - 1);
  int ecl = cl >> 1, ecr = cr >> 1;

  float e[3][4];
  int ers0 = max(2 * i - 1, 0) >> 1;
  int ers2 = min(2 * i + 2, n - 1) >> 1;
  const int ers[3] = {ers0, i, ers2};
#pragma unroll
  for (int t = 0; t < 3; ++t) {
    const float* erow = E1 + (size_t)ers[t] * h;
    e[t][0] = erow[ecl];
    e[t][1] = erow[2 * J];
    e[t][2] = erow[2 * J + 1];
    e[t][3] = erow[ecr];
  }

  float w[4][6];
  const int tmap[4] = {0, 1, 1, 2};
#pragma unroll
  for (int rr = 0; rr < 4; ++rr) {
    int R = min(max(2 * i - 1 + rr, 0), n - 1);
    int t = tmap[rr];
    const float* vrow = v + (size_t)R * n;
    float4 m = *reinterpret_cast<const float4*>(vrow + c0);
    w[rr][0] = vrow[cl] - e[t][0];
    w[rr][1] = m.x - e[t][1];
    w[rr][2] = m.y - e[t][1];
    w[rr][3] = m.z - e[t][2];
    w[rr][4] = m.w - e[t][2];
    w[rr][5] = vrow[cr] - e[t][3];
  }
#pragma unroll
  for (int a = 0; a < 2; ++a) {
    float4 o;
#pragma unroll
    for (int qq = 0; qq < 4; ++qq) {
      float ce = w[a + 1][qq + 1];
      float sm = CW * w[a][qq + 1] - CW * w[a + 2][qq + 1]
               + CW * w[a + 1][qq] + ce - CW * w[a + 1][qq + 2];
      (&o.x)[qq] = ce - sm;
    }
    *reinterpret_cast<float4*>(out + (size_t)(2 * i + a) * n + c0) = o;
  }
}

// ---------------------------------------------------------------------------
extern "C" void kernel_launch(void* const* d_in, const int* in_sizes, int n_in,
                              void* d_out, int out_size, void* d_ws, size_t ws_size,
                              hipStream_t stream) {
  (void)in_sizes; (void)n_in; (void)out_size;
  float* u = (float*)d_in[0];
  float* out = (float*)d_out;
  char* ws = (char*)d_ws;

  size_t off = 0;
  auto alloc = [&](size_t elems) {
    float* p = (float*)(ws + off);
    off += (elems * sizeof(float) + 255) & ~(size_t)255;
    return p;
  };
  float* r1 = alloc(2048 * 2048);
  float* r2 = alloc(1024 * 1024);
  float* r3 = alloc(512 * 512);
  float* r4 = alloc(256 * 256);
  float* r5 = alloc(128 * 128);
  float* E2 = alloc(1024 * 1024);
  float* E1 = alloc(2048 * 2048);
  size_t pool = off;
  const size_t VB = (size_t)4096 * 4096 * sizeof(float);
  bool big = ws_size >= pool + VB;
  float* vws = (float*)(ws + pool);

  dim3 b(64, 4);
  auto iterate = [&](const float* vin, float* vout) {
    k_sr_chain<<<dim3(32, 32), 256, 0, stream>>>(vin, r1, r2, r3, r4, r5);
    k_mid<<<dim3(16, 16), 256, 0, stream>>>(r5, r4, r3, r2, E2);
    k_up<<<dim3(8, 256), b, 0, stream>>>(E2, r1, E1, 2048);
    k_final<<<dim3(16, 512), b, 0, stream>>>(vin, E1, vout);
  };

  if (big) {
    iterate(u, vws);
    iterate(vws, out);
    iterate(out, vws);
    iterate(vws, out);
  } else {
    iterate(u, out);
    iterate(out, u);
    iterate(u, out);
    iterate(out, u);
    hipMemcpyAsync(out, u, VB, hipMemcpyDeviceToDevice, stream);
  }
}